// Round 4
// baseline (466.820 us; speedup 1.0000x reference)
//
#include <hip/hip_runtime.h>

// I/O: float32 (per reference). Internal compute: bf16 MFMA (2%-relative
// threshold; measured absmax 0.0156 vs 0.0615 budget).
//
// R8: explicit software pipeline. R7 post-mortem: halving weight traffic
// changed nothing (92.6->95.9us); recalibrated MFMA cost is ~19.4 cyc/SIMD
// (not 4.85 -- that was per-CU), so floors are MFMA 24us / HBM 28us / LDS
// 10us, all <25% busy at 96us wall. Shared invariant of all 84-128us
// variants: per-kt operand loads feed same-kt MFMAs with VGPR budget exactly
// tight (R7: acc96+operands=128=reported) => compiler CANNOT prefetch;
// every kt exposes ~120cyc LDS + ~200cyc L2 latency serially with only
// 2 waves/SIMD covering. Fix: named A/B register double-buffers for hb/wf
// in L1/L2/L3 (static indices only), geometry and indexing identical to R7.
// launch_bounds(512,2) gives 256-reg budget: L3 ~165, L2 ~210 regs, no spill.
// Stores stay plain (R7: NT was the 206->160MB write amplifier).

typedef __attribute__((ext_vector_type(4))) float  floatx4;
typedef __attribute__((ext_vector_type(8))) short  shortx8;
typedef __attribute__((ext_vector_type(4))) short  shortx4;

__device__ __forceinline__ short f2bf(float f) {
    unsigned u = __builtin_bit_cast(unsigned, f);
    u += 0x7fffu + ((u >> 16) & 1u);   // RTNE
    return (short)(u >> 16);
}

__device__ __forceinline__ shortx8 cvt8(const float* __restrict__ p) {
    floatx4 a = *(const floatx4*)p;
    floatx4 b = *(const floatx4*)(p + 4);
    shortx8 r;
    r[0] = f2bf(a[0]); r[1] = f2bf(a[1]); r[2] = f2bf(a[2]); r[3] = f2bf(a[3]);
    r[4] = f2bf(b[0]); r[5] = f2bf(b[1]); r[6] = f2bf(b[2]); r[7] = f2bf(b[3]);
    return r;
}

// Single-launch repack of W1/W2/W3 (f32 row-major [K,N]) into bf16 MFMA
// fragment order. Tile rel=(nt*KT+kt): lane l holds
// W[kt*32+(l>>4)*8+j][nt*16+(l&15)], j=0..7, 16B contiguous per lane.
// (Used as the A operand: mfma(w_frag, x_frag) computes the transposed tile,
// so D reg index runs along contiguous output columns.)
__global__ void repack_all(const float* __restrict__ W1,
                           const float* __restrict__ W2,
                           const float* __restrict__ W3,
                           short* __restrict__ ws) {
    int t = blockIdx.x * blockDim.x + threadIdx.x;
    int tile = t >> 6, lane = t & 63;
    const float* src; short* dst; int N, KT, rel;
    if (tile < 192)       { src = W1; dst = ws;                  N = 256;  KT = 12; rel = tile; }
    else if (tile < 448)  { src = W2; dst = ws + 98304;          N = 512;  KT = 8;  rel = tile - 192; }
    else if (tile < 1600) { src = W3; dst = ws + 98304 + 131072; N = 1152; KT = 16; rel = tile - 448; }
    else return;
    int nt = rel / KT, kt = rel - nt * KT;
    int col  = nt * 16 + (lane & 15);
    int row0 = kt * 32 + (lane >> 4) * 8;
    shortx8 v;
#pragma unroll
    for (int j = 0; j < 8; ++j) v[j] = f2bf(src[(row0 + j) * N + col]);
    *(shortx8*)(dst + rel * 512 + lane * 8) = v;
}

__global__ __launch_bounds__(512, 2) void fused_mlp(
    const float* __restrict__ content, const float* __restrict__ motion,
    const float* __restrict__ b1, const float* __restrict__ b2,
    const float* __restrict__ b3,
    const short* __restrict__ w1p, const short* __restrict__ w2p,
    const short* __restrict__ w3p, float* __restrict__ out)
{
    __shared__ short hbuf[128 * 520];  // 133,120 B: h2 view stride 520; h1 view stride 264

    const int tid  = threadIdx.x;
    const int lane = tid & 63;
    const int w    = tid >> 6;        // wave 0..7: output-column-strip owner
    const int l15  = lane & 15;
    const int q    = lane >> 4;       // 0..3
    const int m0   = blockIdx.x * 128;
    const int bidx = blockIdx.x >> 2; // batch element (4 blocks per batch row)

    // ---------------- Layer 1: X[128,384] @ W1 -> h1[128,256] ----------------
    {
        floatx4 accC[2]    = {};      // content contribution (token-independent)
        floatx4 accM[8][2] = {};      // motion contribution per token tile
        const float* crow  = content + bidx * 256;
        const short* w1b   = w1p + (w * 2) * 12 * 512 + lane * 8;  // + (nt*12+kt)*512

        // content half: k = 0..255, computed ONCE (identical for all tokens)
        {
            shortx8 xcA, xcB, wA[2], wB[2];
            xcA = cvt8(crow + 0 * 32 + q * 8);
#pragma unroll
            for (int nt = 0; nt < 2; ++nt) wA[nt] = *(const shortx8*)(w1b + (nt * 12 + 0) * 512);
#pragma unroll
            for (int kt = 0; kt < 8; kt += 2) {
                xcB = cvt8(crow + (kt + 1) * 32 + q * 8);
#pragma unroll
                for (int nt = 0; nt < 2; ++nt) wB[nt] = *(const shortx8*)(w1b + (nt * 12 + kt + 1) * 512);
#pragma unroll
                for (int nt = 0; nt < 2; ++nt)
                    accC[nt] = __builtin_amdgcn_mfma_f32_16x16x32_bf16(wA[nt], xcA, accC[nt], 0, 0, 0);
                if (kt + 2 < 8) {
                    xcA = cvt8(crow + (kt + 2) * 32 + q * 8);
#pragma unroll
                    for (int nt = 0; nt < 2; ++nt) wA[nt] = *(const shortx8*)(w1b + (nt * 12 + kt + 2) * 512);
                }
#pragma unroll
                for (int nt = 0; nt < 2; ++nt)
                    accC[nt] = __builtin_amdgcn_mfma_f32_16x16x32_bf16(wB[nt], xcB, accC[nt], 0, 0, 0);
            }
        }
        // motion half: k = 256..383 (kt = 8..11)
        {
            shortx8 xbA[8], xbB[8], wA[2], wB[2];
#pragma unroll
            for (int tt = 0; tt < 8; ++tt)
                xbA[tt] = cvt8(motion + (m0 + tt * 16 + l15) * 128 + (8 * 32 - 256) + q * 8);
#pragma unroll
            for (int nt = 0; nt < 2; ++nt) wA[nt] = *(const shortx8*)(w1b + (nt * 12 + 8) * 512);
#pragma unroll
            for (int kt = 8; kt < 12; kt += 2) {
#pragma unroll
                for (int tt = 0; tt < 8; ++tt)
                    xbB[tt] = cvt8(motion + (m0 + tt * 16 + l15) * 128 + ((kt + 1) * 32 - 256) + q * 8);
#pragma unroll
                for (int nt = 0; nt < 2; ++nt) wB[nt] = *(const shortx8*)(w1b + (nt * 12 + kt + 1) * 512);
#pragma unroll
                for (int nt = 0; nt < 2; ++nt)
#pragma unroll
                    for (int tt = 0; tt < 8; ++tt)
                        accM[tt][nt] = __builtin_amdgcn_mfma_f32_16x16x32_bf16(wA[nt], xbA[tt], accM[tt][nt], 0, 0, 0);
                if (kt + 2 < 12) {
#pragma unroll
                    for (int tt = 0; tt < 8; ++tt)
                        xbA[tt] = cvt8(motion + (m0 + tt * 16 + l15) * 128 + ((kt + 2) * 32 - 256) + q * 8);
#pragma unroll
                    for (int nt = 0; nt < 2; ++nt) wA[nt] = *(const shortx8*)(w1b + (nt * 12 + kt + 2) * 512);
                }
#pragma unroll
                for (int nt = 0; nt < 2; ++nt)
#pragma unroll
                    for (int tt = 0; tt < 8; ++tt)
                        accM[tt][nt] = __builtin_amdgcn_mfma_f32_16x16x32_bf16(wB[nt], xbB[tt], accM[tt][nt], 0, 0, 0);
            }
        }
#pragma unroll
        for (int nt = 0; nt < 2; ++nt) {
            const int colb = (w * 2 + nt) * 16 + q * 4;
            const floatx4 bias = *(const floatx4*)(b1 + colb);
#pragma unroll
            for (int tt = 0; tt < 8; ++tt) {
                shortx4 pk;
#pragma unroll
                for (int r = 0; r < 4; ++r) {
                    float v = accM[tt][nt][r] + accC[nt][r] + bias[r];
                    v = (v >= 0.f) ? v : 0.2f * v;
                    pk[r] = f2bf(v);
                }
                *(shortx4*)(&hbuf[(tt * 16 + l15) * 264 + colb]) = pk;  // 8B ds_write
            }
        }
    }
    __syncthreads();

    // ---------------- Layer 2: h1[128,256] @ W2 -> h2[128,512] ----------------
    {
        floatx4 acc[8][4] = {};
        const short* w2b = w2p + (w * 4) * 8 * 512 + lane * 8;  // + (nt*8+kt)*512
        shortx8 hbA[8], hbB[8], wA[4], wB[4];
#pragma unroll
        for (int tt = 0; tt < 8; ++tt)
            hbA[tt] = *(const shortx8*)(&hbuf[(tt * 16 + l15) * 264 + 0 * 32 + q * 8]);
#pragma unroll
        for (int nt = 0; nt < 4; ++nt) wA[nt] = *(const shortx8*)(w2b + (nt * 8 + 0) * 512);
#pragma unroll
        for (int kt = 0; kt < 8; kt += 2) {
#pragma unroll
            for (int tt = 0; tt < 8; ++tt)
                hbB[tt] = *(const shortx8*)(&hbuf[(tt * 16 + l15) * 264 + (kt + 1) * 32 + q * 8]);
#pragma unroll
            for (int nt = 0; nt < 4; ++nt) wB[nt] = *(const shortx8*)(w2b + (nt * 8 + kt + 1) * 512);
#pragma unroll
            for (int nt = 0; nt < 4; ++nt)
#pragma unroll
                for (int tt = 0; tt < 8; ++tt)
                    acc[tt][nt] = __builtin_amdgcn_mfma_f32_16x16x32_bf16(wA[nt], hbA[tt], acc[tt][nt], 0, 0, 0);
            if (kt + 2 < 8) {
#pragma unroll
                for (int tt = 0; tt < 8; ++tt)
                    hbA[tt] = *(const shortx8*)(&hbuf[(tt * 16 + l15) * 264 + (kt + 2) * 32 + q * 8]);
#pragma unroll
                for (int nt = 0; nt < 4; ++nt) wA[nt] = *(const shortx8*)(w2b + (nt * 8 + kt + 2) * 512);
            }
#pragma unroll
            for (int nt = 0; nt < 4; ++nt)
#pragma unroll
                for (int tt = 0; tt < 8; ++tt)
                    acc[tt][nt] = __builtin_amdgcn_mfma_f32_16x16x32_bf16(wB[nt], hbB[tt], acc[tt][nt], 0, 0, 0);
        }
        __syncthreads();   // all h1 reads complete before h2 overwrites buffer
#pragma unroll
        for (int nt = 0; nt < 4; ++nt) {
            const int colb = (w * 4 + nt) * 16 + q * 4;
            const floatx4 bias = *(const floatx4*)(b2 + colb);
#pragma unroll
            for (int tt = 0; tt < 8; ++tt) {
                shortx4 pk;
#pragma unroll
                for (int r = 0; r < 4; ++r) {
                    float v = acc[tt][nt][r] + bias[r];
                    v = (v >= 0.f) ? v : 0.2f * v;
                    pk[r] = f2bf(v);
                }
                *(shortx4*)(&hbuf[(tt * 16 + l15) * 520 + colb]) = pk;  // 8B ds_write
            }
        }
    }
    __syncthreads();

    // ----- Layer 3: h2[128,512] @ W3 -> out[128,1152], 3 passes of 48 cols/wave -----
#pragma unroll 1
    for (int gi = 0; gi < 3; ++gi) {
        floatx4 acc[8][3] = {};   // 96 accs
        const short* w3b = w3p + (w * 9 + gi * 3) * 16 * 512 + lane * 8;  // + (nt*16+kt)*512
        shortx8 hbA[8], hbB[8], wA[3], wB[3];
#pragma unroll
        for (int tt = 0; tt < 8; ++tt)
            hbA[tt] = *(const shortx8*)(&hbuf[(tt * 16 + l15) * 520 + 0 * 32 + q * 8]);
#pragma unroll
        for (int nt = 0; nt < 3; ++nt) wA[nt] = *(const shortx8*)(w3b + (nt * 16 + 0) * 512);
#pragma unroll
        for (int kt = 0; kt < 16; kt += 2) {
#pragma unroll
            for (int tt = 0; tt < 8; ++tt)
                hbB[tt] = *(const shortx8*)(&hbuf[(tt * 16 + l15) * 520 + (kt + 1) * 32 + q * 8]);
#pragma unroll
            for (int nt = 0; nt < 3; ++nt) wB[nt] = *(const shortx8*)(w3b + (nt * 16 + kt + 1) * 512);
#pragma unroll
            for (int nt = 0; nt < 3; ++nt)
#pragma unroll
                for (int tt = 0; tt < 8; ++tt)
                    acc[tt][nt] = __builtin_amdgcn_mfma_f32_16x16x32_bf16(wA[nt], hbA[tt], acc[tt][nt], 0, 0, 0);
            if (kt + 2 < 16) {
#pragma unroll
                for (int tt = 0; tt < 8; ++tt)
                    hbA[tt] = *(const shortx8*)(&hbuf[(tt * 16 + l15) * 520 + (kt + 2) * 32 + q * 8]);
#pragma unroll
                for (int nt = 0; nt < 3; ++nt) wA[nt] = *(const shortx8*)(w3b + (nt * 16 + kt + 2) * 512);
            }
#pragma unroll
            for (int nt = 0; nt < 3; ++nt)
#pragma unroll
                for (int tt = 0; tt < 8; ++tt)
                    acc[tt][nt] = __builtin_amdgcn_mfma_f32_16x16x32_bf16(wB[nt], hbB[tt], acc[tt][nt], 0, 0, 0);
        }
#pragma unroll
        for (int nt = 0; nt < 3; ++nt) {
            const int colb = (w * 9 + gi * 3 + nt) * 16 + q * 4;
            const floatx4 bias = *(const floatx4*)(b3 + colb);
#pragma unroll
            for (int tt = 0; tt < 8; ++tt) {
                floatx4 v = acc[tt][nt] + bias;
                *(floatx4*)(out + (size_t)(m0 + tt * 16 + l15) * 1152 + colb) = v;
            }
        }
    }
}

extern "C" void kernel_launch(void* const* d_in, const int* in_sizes, int n_in,
                              void* d_out, int out_size, void* d_ws, size_t ws_size,
                              hipStream_t stream) {
    const float* content = (const float*)d_in[0];  // [64,256]
    const float* motion  = (const float*)d_in[1];  // [64,512,128]
    const float* W1 = (const float*)d_in[2];       // [384,256]
    const float* b1 = (const float*)d_in[3];
    const float* W2 = (const float*)d_in[4];       // [256,512]
    const float* b2 = (const float*)d_in[5];
    const float* W3 = (const float*)d_in[6];       // [512,1152]
    const float* b3 = (const float*)d_in[7];
    float* out = (float*)d_out;

    short* ws  = (short*)d_ws;
    short* w1p = ws;                     // 192 tiles * 512 elems
    short* w2p = ws + 98304;             // 256 tiles * 512
    short* w3p = ws + 98304 + 131072;    // 1152 tiles * 512

    repack_all<<<400, 256, 0, stream>>>(W1, W2, W3, ws);
    fused_mlp<<<256, 512, 0, stream>>>(content, motion, b1, b2, b3,
                                       w1p, w2p, w3p, out);
}

// Round 5
// 458.522 us; speedup vs baseline: 1.0181x; 1.0181x over previous
//
#include <hip/hip_runtime.h>

// I/O: float32 (per reference). Internal compute: bf16 MFMA (2%-relative
// threshold; measured absmax 0.0156 vs 0.0615 budget).
//
// R9: R8 post-mortem -- dbuf-everywhere SPILLED (FETCH 15->376MB = scratch
// traffic): gfx950 unified VGPR+AGPR file means L2's acc(128 AGPR) + dbuf
// operands(96) + addr ~= 290 > 256-reg cap at 2 waves/SIMD. R8 passed
// correctness though, so the dbuf code is verified. R9 keeps R7's L1/L2
// verbatim (R7 measured no-spill at exactly 128V+128A in L2) and pipelines
// ONLY L3 (72% of FLOPs): acc 96 + hbA/hbB 64 + wA/wB 24 + addr ~= 214 <=
// 256. First clean test of the exposed-latency theory on the dominant
// phase. Falsifier: fused_mlp >=88us with FETCH ~15MB => theory dead,
// pivot structurally next round.

typedef __attribute__((ext_vector_type(4))) float  floatx4;
typedef __attribute__((ext_vector_type(8))) short  shortx8;
typedef __attribute__((ext_vector_type(4))) short  shortx4;

__device__ __forceinline__ short f2bf(float f) {
    unsigned u = __builtin_bit_cast(unsigned, f);
    u += 0x7fffu + ((u >> 16) & 1u);   // RTNE
    return (short)(u >> 16);
}

__device__ __forceinline__ shortx8 cvt8(const float* __restrict__ p) {
    floatx4 a = *(const floatx4*)p;
    floatx4 b = *(const floatx4*)(p + 4);
    shortx8 r;
    r[0] = f2bf(a[0]); r[1] = f2bf(a[1]); r[2] = f2bf(a[2]); r[3] = f2bf(a[3]);
    r[4] = f2bf(b[0]); r[5] = f2bf(b[1]); r[6] = f2bf(b[2]); r[7] = f2bf(b[3]);
    return r;
}

// Single-launch repack of W1/W2/W3 (f32 row-major [K,N]) into bf16 MFMA
// fragment order. Tile rel=(nt*KT+kt): lane l holds
// W[kt*32+(l>>4)*8+j][nt*16+(l&15)], j=0..7, 16B contiguous per lane.
// (Used as the A operand: mfma(w_frag, x_frag) computes the transposed tile,
// so D reg index runs along contiguous output columns.)
__global__ void repack_all(const float* __restrict__ W1,
                           const float* __restrict__ W2,
                           const float* __restrict__ W3,
                           short* __restrict__ ws) {
    int t = blockIdx.x * blockDim.x + threadIdx.x;
    int tile = t >> 6, lane = t & 63;
    const float* src; short* dst; int N, KT, rel;
    if (tile < 192)       { src = W1; dst = ws;                  N = 256;  KT = 12; rel = tile; }
    else if (tile < 448)  { src = W2; dst = ws + 98304;          N = 512;  KT = 8;  rel = tile - 192; }
    else if (tile < 1600) { src = W3; dst = ws + 98304 + 131072; N = 1152; KT = 16; rel = tile - 448; }
    else return;
    int nt = rel / KT, kt = rel - nt * KT;
    int col  = nt * 16 + (lane & 15);
    int row0 = kt * 32 + (lane >> 4) * 8;
    shortx8 v;
#pragma unroll
    for (int j = 0; j < 8; ++j) v[j] = f2bf(src[(row0 + j) * N + col]);
    *(shortx8*)(dst + rel * 512 + lane * 8) = v;
}

__global__ __launch_bounds__(512, 2) void fused_mlp(
    const float* __restrict__ content, const float* __restrict__ motion,
    const float* __restrict__ b1, const float* __restrict__ b2,
    const float* __restrict__ b3,
    const short* __restrict__ w1p, const short* __restrict__ w2p,
    const short* __restrict__ w3p, float* __restrict__ out)
{
    __shared__ short hbuf[128 * 520];  // 133,120 B: h2 view stride 520; h1 view stride 264

    const int tid  = threadIdx.x;
    const int lane = tid & 63;
    const int w    = tid >> 6;        // wave 0..7: output-column-strip owner
    const int l15  = lane & 15;
    const int q    = lane >> 4;       // 0..3
    const int m0   = blockIdx.x * 128;
    const int bidx = blockIdx.x >> 2; // batch element (4 blocks per batch row)

    // ---------------- Layer 1: X[128,384] @ W1 -> h1[128,256] ----------------
    // (verbatim R7: small phase, keep pressure low)
    {
        floatx4 accC[2]    = {};      // content contribution (token-independent)
        floatx4 accM[8][2] = {};      // motion contribution per token tile
        const float* crow = content + bidx * 256;
        // content half: k = 0..255, computed ONCE (identical for all tokens)
#pragma unroll
        for (int kt = 0; kt < 8; ++kt) {
            shortx8 xb = cvt8(crow + kt * 32 + q * 8);
#pragma unroll
            for (int nt = 0; nt < 2; ++nt) {
                shortx8 wf = *(const shortx8*)(w1p + ((w * 2 + nt) * 12 + kt) * 512 + lane * 8);
                accC[nt] = __builtin_amdgcn_mfma_f32_16x16x32_bf16(wf, xb, accC[nt], 0, 0, 0);
            }
        }
        // motion half: k = 256..383
#pragma unroll
        for (int kt = 8; kt < 12; ++kt) {
            shortx8 xb[8];
#pragma unroll
            for (int tt = 0; tt < 8; ++tt)
                xb[tt] = cvt8(motion + (m0 + tt * 16 + l15) * 128 + (kt * 32 - 256) + q * 8);
#pragma unroll
            for (int nt = 0; nt < 2; ++nt) {
                shortx8 wf = *(const shortx8*)(w1p + ((w * 2 + nt) * 12 + kt) * 512 + lane * 8);
#pragma unroll
                for (int tt = 0; tt < 8; ++tt)
                    accM[tt][nt] = __builtin_amdgcn_mfma_f32_16x16x32_bf16(wf, xb[tt], accM[tt][nt], 0, 0, 0);
            }
        }
#pragma unroll
        for (int nt = 0; nt < 2; ++nt) {
            const int colb = (w * 2 + nt) * 16 + q * 4;
            const floatx4 bias = *(const floatx4*)(b1 + colb);
#pragma unroll
            for (int tt = 0; tt < 8; ++tt) {
                shortx4 pk;
#pragma unroll
                for (int r = 0; r < 4; ++r) {
                    float v = accM[tt][nt][r] + accC[nt][r] + bias[r];
                    v = (v >= 0.f) ? v : 0.2f * v;
                    pk[r] = f2bf(v);
                }
                *(shortx4*)(&hbuf[(tt * 16 + l15) * 264 + colb]) = pk;  // 8B ds_write
            }
        }
    }
    __syncthreads();

    // ---------------- Layer 2: h1[128,256] @ W2 -> h2[128,512] ----------------
    // (verbatim R7: acc[8][4]=128 AGPR leaves no dbuf headroom at 256-reg cap)
    {
        floatx4 acc[8][4] = {};
#pragma unroll
        for (int kt = 0; kt < 8; ++kt) {
            shortx8 hb[8];
#pragma unroll
            for (int tt = 0; tt < 8; ++tt)
                hb[tt] = *(const shortx8*)(&hbuf[(tt * 16 + l15) * 264 + kt * 32 + q * 8]);
#pragma unroll
            for (int nt = 0; nt < 4; ++nt) {
                shortx8 wf = *(const shortx8*)(w2p + ((w * 4 + nt) * 8 + kt) * 512 + lane * 8);
#pragma unroll
                for (int tt = 0; tt < 8; ++tt)
                    acc[tt][nt] = __builtin_amdgcn_mfma_f32_16x16x32_bf16(wf, hb[tt], acc[tt][nt], 0, 0, 0);
            }
        }
        __syncthreads();   // all h1 reads complete before h2 overwrites buffer
#pragma unroll
        for (int nt = 0; nt < 4; ++nt) {
            const int colb = (w * 4 + nt) * 16 + q * 4;
            const floatx4 bias = *(const floatx4*)(b2 + colb);
#pragma unroll
            for (int tt = 0; tt < 8; ++tt) {
                shortx4 pk;
#pragma unroll
                for (int r = 0; r < 4; ++r) {
                    float v = acc[tt][nt][r] + bias[r];
                    v = (v >= 0.f) ? v : 0.2f * v;
                    pk[r] = f2bf(v);
                }
                *(shortx4*)(&hbuf[(tt * 16 + l15) * 520 + colb]) = pk;  // 8B ds_write
            }
        }
    }
    __syncthreads();

    // ----- Layer 3: h2[128,512] @ W3 -> out[128,1152], 3 passes of 48 cols/wave -----
    // Pipelined (R8's L3, correctness-verified): acc 96 + hbA/hbB 64 + wA/wB 24
    // + addr ~= 214 <= 256-reg cap -> no spill, operand latency hidden one
    // kt-step (~466 SIMD-cyc of MFMA) ahead.
#pragma unroll 1
    for (int gi = 0; gi < 3; ++gi) {
        floatx4 acc[8][3] = {};   // 96 accs
        const short* w3b = w3p + (w * 9 + gi * 3) * 16 * 512 + lane * 8;  // + (nt*16+kt)*512
        shortx8 hbA[8], hbB[8], wA[3], wB[3];
#pragma unroll
        for (int tt = 0; tt < 8; ++tt)
            hbA[tt] = *(const shortx8*)(&hbuf[(tt * 16 + l15) * 520 + 0 * 32 + q * 8]);
#pragma unroll
        for (int nt = 0; nt < 3; ++nt) wA[nt] = *(const shortx8*)(w3b + (nt * 16 + 0) * 512);
#pragma unroll
        for (int kt = 0; kt < 16; kt += 2) {
#pragma unroll
            for (int tt = 0; tt < 8; ++tt)
                hbB[tt] = *(const shortx8*)(&hbuf[(tt * 16 + l15) * 520 + (kt + 1) * 32 + q * 8]);
#pragma unroll
            for (int nt = 0; nt < 3; ++nt) wB[nt] = *(const shortx8*)(w3b + (nt * 16 + kt + 1) * 512);
#pragma unroll
            for (int nt = 0; nt < 3; ++nt)
#pragma unroll
                for (int tt = 0; tt < 8; ++tt)
                    acc[tt][nt] = __builtin_amdgcn_mfma_f32_16x16x32_bf16(wA[nt], hbA[tt], acc[tt][nt], 0, 0, 0);
            if (kt + 2 < 16) {
#pragma unroll
                for (int tt = 0; tt < 8; ++tt)
                    hbA[tt] = *(const shortx8*)(&hbuf[(tt * 16 + l15) * 520 + (kt + 2) * 32 + q * 8]);
#pragma unroll
                for (int nt = 0; nt < 3; ++nt) wA[nt] = *(const shortx8*)(w3b + (nt * 16 + kt + 2) * 512);
            }
#pragma unroll
            for (int nt = 0; nt < 3; ++nt)
#pragma unroll
                for (int tt = 0; tt < 8; ++tt)
                    acc[tt][nt] = __builtin_amdgcn_mfma_f32_16x16x32_bf16(wB[nt], hbB[tt], acc[tt][nt], 0, 0, 0);
        }
#pragma unroll
        for (int nt = 0; nt < 3; ++nt) {
            const int colb = (w * 9 + gi * 3 + nt) * 16 + q * 4;
            const floatx4 bias = *(const floatx4*)(b3 + colb);
#pragma unroll
            for (int tt = 0; tt < 8; ++tt) {
                floatx4 v = acc[tt][nt] + bias;
                *(floatx4*)(out + (size_t)(m0 + tt * 16 + l15) * 1152 + colb) = v;
            }
        }
    }
}

extern "C" void kernel_launch(void* const* d_in, const int* in_sizes, int n_in,
                              void* d_out, int out_size, void* d_ws, size_t ws_size,
                              hipStream_t stream) {
    const float* content = (const float*)d_in[0];  // [64,256]
    const float* motion  = (const float*)d_in[1];  // [64,512,128]
    const float* W1 = (const float*)d_in[2];       // [384,256]
    const float* b1 = (const float*)d_in[3];
    const float* W2 = (const float*)d_in[4];       // [256,512]
    const float* b2 = (const float*)d_in[5];
    const float* W3 = (const float*)d_in[6];       // [512,1152]
    const float* b3 = (const float*)d_in[7];
    float* out = (float*)d_out;

    short* ws  = (short*)d_ws;
    short* w1p = ws;                     // 192 tiles * 512 elems
    short* w2p = ws + 98304;             // 256 tiles * 512
    short* w3p = ws + 98304 + 131072;    // 1152 tiles * 512

    repack_all<<<400, 256, 0, stream>>>(W1, W2, W3, ws);
    fused_mlp<<<256, 512, 0, stream>>>(content, motion, b1, b2, b3,
                                       w1p, w2p, w3p, out);
}

// Round 6
// 234.924 us; speedup vs baseline: 1.9871x; 1.9518x over previous
//
#include <hip/hip_runtime.h>

// I/O: float32 (per reference). Internal compute: bf16 MFMA (2%-relative
// threshold; measured absmax 0.0156 vs 0.0615 budget).
//
// R10: R8/R9 post-mortem -- the spill (FETCH 15->370MB) was caused by
// '#pragma unroll' (FULL unroll) on the dbuf'd kt loop: scheduler hoisted
// 8 iterations of loads, exploding live ranges (m132 lesson). Also R7
// geometry had zero reg headroom (L2 = 128 arch + 128 acc exactly).
// R10 returns to R5's proven geometry (64-token blocks, 512 thr, grid 512,
// launch_bounds(512,4): 2 blocks/CU, 16 waves/CU, VGPR_Count 64 measured,
// 92.6us) and adds the L3 dbuf ONLY, with '#pragma unroll 1' on the kt
// loop so the hand-pipeline is the only pipeline. L3 budget: acc 48 (AGPR)
// + hbA/hbB 32 + wA/wB 24 + addr ~= 128 total. Weight loads (L2, ~200cyc)
// issue before ds_reads (~120cyc) each step; each load batch is covered by
// 12 MFMAs (~233 SIMD-cyc) of the other buffer.
// Gate: FETCH ~15MB / WRITE ~160MB = no spill. Falsifier: clean FETCH but
// fused_mlp >= 88us kills the latency-exposure theory.

typedef __attribute__((ext_vector_type(4))) float  floatx4;
typedef __attribute__((ext_vector_type(8))) short  shortx8;
typedef __attribute__((ext_vector_type(4))) short  shortx4;

__device__ __forceinline__ short f2bf(float f) {
    unsigned u = __builtin_bit_cast(unsigned, f);
    u += 0x7fffu + ((u >> 16) & 1u);   // RTNE
    return (short)(u >> 16);
}

__device__ __forceinline__ shortx8 cvt8(const float* __restrict__ p) {
    floatx4 a = *(const floatx4*)p;
    floatx4 b = *(const floatx4*)(p + 4);
    shortx8 r;
    r[0] = f2bf(a[0]); r[1] = f2bf(a[1]); r[2] = f2bf(a[2]); r[3] = f2bf(a[3]);
    r[4] = f2bf(b[0]); r[5] = f2bf(b[1]); r[6] = f2bf(b[2]); r[7] = f2bf(b[3]);
    return r;
}

// Single-launch repack of W1/W2/W3 (f32 row-major [K,N]) into bf16 MFMA
// fragment order. Tile rel=(nt*KT+kt): lane l holds
// W[kt*32+(l>>4)*8+j][nt*16+(l&15)], j=0..7, 16B contiguous per lane.
// (Used as the A operand: mfma(w_frag, x_frag) computes the transposed tile,
// so D reg index runs along contiguous output columns.)
__global__ void repack_all(const float* __restrict__ W1,
                           const float* __restrict__ W2,
                           const float* __restrict__ W3,
                           short* __restrict__ ws) {
    int t = blockIdx.x * blockDim.x + threadIdx.x;
    int tile = t >> 6, lane = t & 63;
    const float* src; short* dst; int N, KT, rel;
    if (tile < 192)       { src = W1; dst = ws;                  N = 256;  KT = 12; rel = tile; }
    else if (tile < 448)  { src = W2; dst = ws + 98304;          N = 512;  KT = 8;  rel = tile - 192; }
    else if (tile < 1600) { src = W3; dst = ws + 98304 + 131072; N = 1152; KT = 16; rel = tile - 448; }
    else return;
    int nt = rel / KT, kt = rel - nt * KT;
    int col  = nt * 16 + (lane & 15);
    int row0 = kt * 32 + (lane >> 4) * 8;
    shortx8 v;
#pragma unroll
    for (int j = 0; j < 8; ++j) v[j] = f2bf(src[(row0 + j) * N + col]);
    *(shortx8*)(dst + rel * 512 + lane * 8) = v;
}

__global__ __launch_bounds__(512, 4) void fused_mlp(
    const float* __restrict__ content, const float* __restrict__ motion,
    const float* __restrict__ b1, const float* __restrict__ b2,
    const float* __restrict__ b3,
    const short* __restrict__ w1p, const short* __restrict__ w2p,
    const short* __restrict__ w3p, float* __restrict__ out)
{
    __shared__ short hbuf[64 * 520];   // h2 view: stride 520; h1 view: stride 264

    const int tid  = threadIdx.x;
    const int lane = tid & 63;
    const int w    = tid >> 6;        // wave 0..7: output-column-strip owner
    const int l15  = lane & 15;
    const int q    = lane >> 4;       // 0..3
    const int m0   = blockIdx.x * 64;
    const int bidx = m0 >> 9;         // batch element

    // ---------------- Layer 1: X[64,384] @ W1 -> h1[64,256] ----------------
    // (verbatim R5)
    {
        floatx4 accC[2]    = {};      // content contribution (token-independent)
        floatx4 accM[4][2] = {};      // motion contribution per token tile
        const float* crow = content + bidx * 256;
#pragma unroll
        for (int kt = 0; kt < 8; ++kt) {
            shortx8 xb = cvt8(crow + kt * 32 + q * 8);
#pragma unroll
            for (int nt = 0; nt < 2; ++nt) {
                shortx8 wf = *(const shortx8*)(w1p + ((w * 2 + nt) * 12 + kt) * 512 + lane * 8);
                accC[nt] = __builtin_amdgcn_mfma_f32_16x16x32_bf16(wf, xb, accC[nt], 0, 0, 0);
            }
        }
#pragma unroll
        for (int kt = 8; kt < 12; ++kt) {
            shortx8 xb[4];
#pragma unroll
            for (int tt = 0; tt < 4; ++tt)
                xb[tt] = cvt8(motion + (m0 + tt * 16 + l15) * 128 + (kt * 32 - 256) + q * 8);
#pragma unroll
            for (int nt = 0; nt < 2; ++nt) {
                shortx8 wf = *(const shortx8*)(w1p + ((w * 2 + nt) * 12 + kt) * 512 + lane * 8);
#pragma unroll
                for (int tt = 0; tt < 4; ++tt)
                    accM[tt][nt] = __builtin_amdgcn_mfma_f32_16x16x32_bf16(wf, xb[tt], accM[tt][nt], 0, 0, 0);
            }
        }
#pragma unroll
        for (int nt = 0; nt < 2; ++nt) {
            const int colb = (w * 2 + nt) * 16 + q * 4;
            const floatx4 bias = *(const floatx4*)(b1 + colb);
#pragma unroll
            for (int tt = 0; tt < 4; ++tt) {
                shortx4 pk;
#pragma unroll
                for (int r = 0; r < 4; ++r) {
                    float v = accM[tt][nt][r] + accC[nt][r] + bias[r];
                    v = (v >= 0.f) ? v : 0.2f * v;
                    pk[r] = f2bf(v);
                }
                *(shortx4*)(&hbuf[(tt * 16 + l15) * 264 + colb]) = pk;  // 8B ds_write
            }
        }
    }
    __syncthreads();

    // ---------------- Layer 2: h1[64,256] @ W2 -> h2[64,512] ----------------
    // (verbatim R5)
    {
        floatx4 acc[4][4] = {};
#pragma unroll
        for (int kt = 0; kt < 8; ++kt) {
            shortx8 hb[4];
#pragma unroll
            for (int tt = 0; tt < 4; ++tt)
                hb[tt] = *(const shortx8*)(&hbuf[(tt * 16 + l15) * 264 + kt * 32 + q * 8]);
#pragma unroll
            for (int nt = 0; nt < 4; ++nt) {
                shortx8 wf = *(const shortx8*)(w2p + ((w * 4 + nt) * 8 + kt) * 512 + lane * 8);
#pragma unroll
                for (int tt = 0; tt < 4; ++tt)
                    acc[tt][nt] = __builtin_amdgcn_mfma_f32_16x16x32_bf16(wf, hb[tt], acc[tt][nt], 0, 0, 0);
            }
        }
        __syncthreads();   // all h1 reads complete before h2 overwrites buffer
#pragma unroll
        for (int nt = 0; nt < 4; ++nt) {
            const int colb = (w * 4 + nt) * 16 + q * 4;
            const floatx4 bias = *(const floatx4*)(b2 + colb);
#pragma unroll
            for (int tt = 0; tt < 4; ++tt) {
                shortx4 pk;
#pragma unroll
                for (int r = 0; r < 4; ++r) {
                    float v = acc[tt][nt][r] + bias[r];
                    v = (v >= 0.f) ? v : 0.2f * v;
                    pk[r] = f2bf(v);
                }
                *(shortx4*)(&hbuf[(tt * 16 + l15) * 520 + colb]) = pk;  // 8B ds_write
            }
        }
    }
    __syncthreads();

    // -------- Layer 3: h2[64,512] @ W3 -> out[64,1152], 3 passes of 48 cols --------
    // Hand-pipelined A/B buffers; '#pragma unroll 1' on kt so the compiler
    // cannot hoist loads beyond the 1-step window (R8/R9 spill fix).
#pragma unroll 1
    for (int gi = 0; gi < 3; ++gi) {
        floatx4 acc[4][3] = {};   // 48 accs (AGPR)
        const short* w3b = w3p + (w * 9 + gi * 3) * 16 * 512 + lane * 8;  // + (nt*16+kt)*512
        shortx8 hbA[4], hbB[4], wA[3], wB[3];
#pragma unroll
        for (int nt = 0; nt < 3; ++nt) wA[nt] = *(const shortx8*)(w3b + (nt * 16 + 0) * 512);
#pragma unroll
        for (int tt = 0; tt < 4; ++tt)
            hbA[tt] = *(const shortx8*)(&hbuf[(tt * 16 + l15) * 520 + 0 * 32 + q * 8]);
#pragma unroll 1
        for (int kt = 0; kt < 16; kt += 2) {
            // issue next-step (kt+1) loads: weights first (longest latency)
#pragma unroll
            for (int nt = 0; nt < 3; ++nt) wB[nt] = *(const shortx8*)(w3b + (nt * 16 + kt + 1) * 512);
#pragma unroll
            for (int tt = 0; tt < 4; ++tt)
                hbB[tt] = *(const shortx8*)(&hbuf[(tt * 16 + l15) * 520 + (kt + 1) * 32 + q * 8]);
            // compute on A (operands loaded one step earlier)
#pragma unroll
            for (int nt = 0; nt < 3; ++nt)
#pragma unroll
                for (int tt = 0; tt < 4; ++tt)
                    acc[tt][nt] = __builtin_amdgcn_mfma_f32_16x16x32_bf16(wA[nt], hbA[tt], acc[tt][nt], 0, 0, 0);
            // issue (kt+2) loads into A
            if (kt + 2 < 16) {
#pragma unroll
                for (int nt = 0; nt < 3; ++nt) wA[nt] = *(const shortx8*)(w3b + (nt * 16 + kt + 2) * 512);
#pragma unroll
                for (int tt = 0; tt < 4; ++tt)
                    hbA[tt] = *(const shortx8*)(&hbuf[(tt * 16 + l15) * 520 + (kt + 2) * 32 + q * 8]);
            }
            // compute on B
#pragma unroll
            for (int nt = 0; nt < 3; ++nt)
#pragma unroll
                for (int tt = 0; tt < 4; ++tt)
                    acc[tt][nt] = __builtin_amdgcn_mfma_f32_16x16x32_bf16(wB[nt], hbB[tt], acc[tt][nt], 0, 0, 0);
        }
#pragma unroll
        for (int nt = 0; nt < 3; ++nt) {
            const int colb = (w * 9 + gi * 3 + nt) * 16 + q * 4;
            const floatx4 bias = *(const floatx4*)(b3 + colb);
#pragma unroll
            for (int tt = 0; tt < 4; ++tt) {
                floatx4 v = acc[tt][nt] + bias;
                *(floatx4*)(out + (size_t)(m0 + tt * 16 + l15) * 1152 + colb) = v;
            }
        }
    }
}

extern "C" void kernel_launch(void* const* d_in, const int* in_sizes, int n_in,
                              void* d_out, int out_size, void* d_ws, size_t ws_size,
                              hipStream_t stream) {
    const float* content = (const float*)d_in[0];  // [64,256]
    const float* motion  = (const float*)d_in[1];  // [64,512,128]
    const float* W1 = (const float*)d_in[2];       // [384,256]
    const float* b1 = (const float*)d_in[3];
    const float* W2 = (const float*)d_in[4];       // [256,512]
    const float* b2 = (const float*)d_in[5];
    const float* W3 = (const float*)d_in[6];       // [512,1152]
    const float* b3 = (const float*)d_in[7];
    float* out = (float*)d_out;

    short* ws  = (short*)d_ws;
    short* w1p = ws;                     // 192 tiles * 512 elems
    short* w2p = ws + 98304;             // 256 tiles * 512
    short* w3p = ws + 98304 + 131072;    // 1152 tiles * 512

    repack_all<<<400, 256, 0, stream>>>(W1, W2, W3, ws);
    fused_mlp<<<512, 512, 0, stream>>>(content, motion, b1, b2, b3,
                                       w1p, w2p, w3p, out);
}

// Round 7
// 229.037 us; speedup vs baseline: 2.0382x; 1.0257x over previous
//
#include <hip/hip_runtime.h>

// I/O: float32 (per reference). Internal compute: bf16 MFMA (2%-relative
// threshold; measured absmax 0.0156 vs 0.0615 budget).
//
// R11: restore R0 (the session-best: fused ~84us inferred from dur-140;
// its coalesced scalar epilogues beat R5's 16B-scatter "vectorized" ones)
// plus two attributed changes:
//  (a) L1 content-dedup in R0 operand order: content fragment is identical
//      for all 4 token tiles -> accumulate accC once (16 MFMAs), copy-init
//      acc[mt][nt]=accC[nt], then add motion kts. Per-element FP order
//      identical to R0 => absmax unchanged. -72 MFMA/wave.
//  (b) L3 register dbuf PINNED with sched_barrier(0) between load-issue and
//      MFMA clusters. R10 showed (VGPR stuck at 64) that without the fence
//      the compiler sinks prefetch loads back to their consumers, deleting
//      the pipeline. With the fence, auto-waitcnt must emit counted
//      vmcnt(3)/lgkmcnt(4) for the OLDER batch while 7 newer loads fly
//      across the 12-MFMA burst -- breaking the per-step load-drain stall
//      (per-CU pipe sums: MFMA 24 + VMEM 27 + VALU 17 + LDS 8 ~= 76us
//      ~= wall => pipes currently serialized by lockstep load-drains).
// Gate: VGPR ~110-128 (prefetch survived), FETCH <=30MB (no spill).
// Falsifier: fused >= 84us => structural plateau, pivot or stop.

typedef __attribute__((ext_vector_type(4))) float  floatx4;
typedef __attribute__((ext_vector_type(8))) short  shortx8;

__device__ __forceinline__ short f2bf(float f) {
    unsigned u = __builtin_bit_cast(unsigned, f);
    u += 0x7fffu + ((u >> 16) & 1u);   // RTNE
    return (short)(u >> 16);
}

__device__ __forceinline__ shortx8 cvt8(const float* __restrict__ p) {
    floatx4 a = *(const floatx4*)p;
    floatx4 b = *(const floatx4*)(p + 4);
    shortx8 r;
    r[0] = f2bf(a[0]); r[1] = f2bf(a[1]); r[2] = f2bf(a[2]); r[3] = f2bf(a[3]);
    r[4] = f2bf(b[0]); r[5] = f2bf(b[1]); r[6] = f2bf(b[2]); r[7] = f2bf(b[3]);
    return r;
}

// Single-launch repack of W1/W2/W3 (f32 row-major [K,N]) into bf16 MFMA-B
// fragment order. Tile rel=(nt*KT+kt): lane l holds
// B[kt*32+(l>>4)*8+j][nt*16+(l&15)], j=0..7, 16B contiguous per lane.
__global__ void repack_all(const float* __restrict__ W1,
                           const float* __restrict__ W2,
                           const float* __restrict__ W3,
                           short* __restrict__ ws) {
    int t = blockIdx.x * blockDim.x + threadIdx.x;
    int tile = t >> 6, lane = t & 63;
    const float* src; short* dst; int N, KT, rel;
    if (tile < 192)       { src = W1; dst = ws;                  N = 256;  KT = 12; rel = tile; }
    else if (tile < 448)  { src = W2; dst = ws + 98304;          N = 512;  KT = 8;  rel = tile - 192; }
    else if (tile < 1600) { src = W3; dst = ws + 98304 + 131072; N = 1152; KT = 16; rel = tile - 448; }
    else return;
    int nt = rel / KT, kt = rel - nt * KT;
    int col  = nt * 16 + (lane & 15);
    int row0 = kt * 32 + (lane >> 4) * 8;
    shortx8 v;
#pragma unroll
    for (int j = 0; j < 8; ++j) v[j] = f2bf(src[(row0 + j) * N + col]);
    *(shortx8*)(dst + rel * 512 + lane * 8) = v;
}

__global__ __launch_bounds__(512, 4) void fused_mlp(
    const float* __restrict__ content, const float* __restrict__ motion,
    const float* __restrict__ b1, const float* __restrict__ b2,
    const float* __restrict__ b3,
    const short* __restrict__ w1p, const short* __restrict__ w2p,
    const short* __restrict__ w3p, float* __restrict__ out)
{
    __shared__ short hbuf[64 * 520];   // h2 view: stride 520; h1 view: stride 264

    const int tid  = threadIdx.x;
    const int lane = tid & 63;
    const int w    = tid >> 6;        // wave 0..7: column-strip owner
    const int l15  = lane & 15;
    const int q    = lane >> 4;       // 0..3
    const int m0   = blockIdx.x * 64;
    const int bidx = m0 >> 9;

    // ---------------- Layer 1: X[64,384] @ W1 -> h1[64,256] ----------------
    {
        floatx4 accC[2] = {};          // content partial sum (token-independent)
        const float* crow = content + bidx * 256;
#pragma unroll
        for (int kt = 0; kt < 8; ++kt) {
            shortx8 a0 = cvt8(crow + kt * 32 + q * 8);   // identical across mt
#pragma unroll
            for (int nt = 0; nt < 2; ++nt) {
                shortx8 bf = *(const shortx8*)(w1p + ((w * 2 + nt) * 12 + kt) * 512 + lane * 8);
                accC[nt] = __builtin_amdgcn_mfma_f32_16x16x32_bf16(a0, bf, accC[nt], 0, 0, 0);
            }
        }
        floatx4 acc[4][2];
#pragma unroll
        for (int mt = 0; mt < 4; ++mt)
#pragma unroll
            for (int nt = 0; nt < 2; ++nt) acc[mt][nt] = accC[nt];
#pragma unroll
        for (int kt = 8; kt < 12; ++kt) {
            const int c0 = kt * 32 + q * 8;
            shortx8 a[4];
#pragma unroll
            for (int mt = 0; mt < 4; ++mt)
                a[mt] = cvt8(motion + (m0 + mt * 16 + l15) * 128 + (c0 - 256));
#pragma unroll
            for (int nt = 0; nt < 2; ++nt) {
                shortx8 bf = *(const shortx8*)(w1p + ((w * 2 + nt) * 12 + kt) * 512 + lane * 8);
#pragma unroll
                for (int mt = 0; mt < 4; ++mt)
                    acc[mt][nt] = __builtin_amdgcn_mfma_f32_16x16x32_bf16(a[mt], bf, acc[mt][nt], 0, 0, 0);
            }
        }
#pragma unroll
        for (int nt = 0; nt < 2; ++nt) {
            const int col = (w * 2 + nt) * 16 + l15;
            const float bias = b1[col];
#pragma unroll
            for (int mt = 0; mt < 4; ++mt)
#pragma unroll
            for (int r = 0; r < 4; ++r) {
                float v = acc[mt][nt][r] + bias;
                v = (v >= 0.f) ? v : 0.2f * v;
                hbuf[(mt * 16 + q * 4 + r) * 264 + col] = f2bf(v);
            }
        }
    }
    __syncthreads();

    // ---------------- Layer 2: h1[64,256] @ W2 -> h2[64,512] ----------------
    // (verbatim R0)
    {
        floatx4 acc[4][4] = {};
#pragma unroll
        for (int kt = 0; kt < 8; ++kt) {
            shortx8 a[4];
#pragma unroll
            for (int mt = 0; mt < 4; ++mt)
                a[mt] = *(const shortx8*)(&hbuf[(mt * 16 + l15) * 264 + kt * 32 + q * 8]);
#pragma unroll
            for (int nt = 0; nt < 4; ++nt) {
                shortx8 bf = *(const shortx8*)(w2p + ((w * 4 + nt) * 8 + kt) * 512 + lane * 8);
#pragma unroll
                for (int mt = 0; mt < 4; ++mt)
                    acc[mt][nt] = __builtin_amdgcn_mfma_f32_16x16x32_bf16(a[mt], bf, acc[mt][nt], 0, 0, 0);
            }
        }
        __syncthreads();   // all h1 reads complete before h2 overwrites buffer
#pragma unroll
        for (int nt = 0; nt < 4; ++nt) {
            const int col = (w * 4 + nt) * 16 + l15;
            const float bias = b2[col];
#pragma unroll
            for (int mt = 0; mt < 4; ++mt)
#pragma unroll
            for (int r = 0; r < 4; ++r) {
                float v = acc[mt][nt][r] + bias;
                v = (v >= 0.f) ? v : 0.2f * v;
                hbuf[(mt * 16 + q * 4 + r) * 520 + col] = f2bf(v);
            }
        }
    }
    __syncthreads();

    // -------- Layer 3: h2[64,512] @ W3 -> out[64,1152], 3 passes of 48 cols --------
    // R0 operand order + epilogue; A/B register dbuf pinned by sched_barrier(0).
#pragma unroll 1
    for (int gi = 0; gi < 3; ++gi) {
        floatx4 acc[4][3] = {};   // 48 accs
        const short* w3b = w3p + (w * 9 + gi * 3) * 16 * 512 + lane * 8;  // + (nt*16+kt)*512
        shortx8 hbA[4], hbB[4], wA[3], wB[3];
#pragma unroll
        for (int nt = 0; nt < 3; ++nt) wA[nt] = *(const shortx8*)(w3b + (nt * 16 + 0) * 512);
#pragma unroll
        for (int mt = 0; mt < 4; ++mt)
            hbA[mt] = *(const shortx8*)(&hbuf[(mt * 16 + l15) * 520 + 0 * 32 + q * 8]);
#pragma unroll 1
        for (int kt = 0; kt < 16; kt += 2) {
            // issue (kt+1) loads; fence pins them BEFORE the A-compute
#pragma unroll
            for (int nt = 0; nt < 3; ++nt) wB[nt] = *(const shortx8*)(w3b + (nt * 16 + kt + 1) * 512);
#pragma unroll
            for (int mt = 0; mt < 4; ++mt)
                hbB[mt] = *(const shortx8*)(&hbuf[(mt * 16 + l15) * 520 + (kt + 1) * 32 + q * 8]);
            __builtin_amdgcn_sched_barrier(0);
            // compute on A: waits only on the OLDER batch (counted vmcnt/lgkmcnt)
#pragma unroll
            for (int nt = 0; nt < 3; ++nt)
#pragma unroll
                for (int mt = 0; mt < 4; ++mt)
                    acc[mt][nt] = __builtin_amdgcn_mfma_f32_16x16x32_bf16(hbA[mt], wA[nt], acc[mt][nt], 0, 0, 0);
            if (kt + 2 < 16) {
#pragma unroll
                for (int nt = 0; nt < 3; ++nt) wA[nt] = *(const shortx8*)(w3b + (nt * 16 + kt + 2) * 512);
#pragma unroll
                for (int mt = 0; mt < 4; ++mt)
                    hbA[mt] = *(const shortx8*)(&hbuf[(mt * 16 + l15) * 520 + (kt + 2) * 32 + q * 8]);
            }
            __builtin_amdgcn_sched_barrier(0);
            // compute on B
#pragma unroll
            for (int nt = 0; nt < 3; ++nt)
#pragma unroll
                for (int mt = 0; mt < 4; ++mt)
                    acc[mt][nt] = __builtin_amdgcn_mfma_f32_16x16x32_bf16(hbB[mt], wB[nt], acc[mt][nt], 0, 0, 0);
        }
        // R0 epilogue: col = lane-consecutive -> 64B-coalesced scalar stores
#pragma unroll
        for (int nt = 0; nt < 3; ++nt) {
            const int col = (w * 9 + gi * 3 + nt) * 16 + l15;
            const float bias = b3[col];
#pragma unroll
            for (int mt = 0; mt < 4; ++mt)
#pragma unroll
            for (int r = 0; r < 4; ++r)
                out[(m0 + mt * 16 + q * 4 + r) * 1152 + col] = acc[mt][nt][r] + bias;
        }
    }
}

extern "C" void kernel_launch(void* const* d_in, const int* in_sizes, int n_in,
                              void* d_out, int out_size, void* d_ws, size_t ws_size,
                              hipStream_t stream) {
    const float* content = (const float*)d_in[0];  // [64,256]
    const float* motion  = (const float*)d_in[1];  // [64,512,128]
    const float* W1 = (const float*)d_in[2];       // [384,256]
    const float* b1 = (const float*)d_in[3];
    const float* W2 = (const float*)d_in[4];       // [256,512]
    const float* b2 = (const float*)d_in[5];
    const float* W3 = (const float*)d_in[6];       // [512,1152]
    const float* b3 = (const float*)d_in[7];
    float* out = (float*)d_out;

    short* ws  = (short*)d_ws;
    short* w1p = ws;                     // 192 tiles * 512 elems
    short* w2p = ws + 98304;             // 256 tiles * 512
    short* w3p = ws + 98304 + 131072;    // 1152 tiles * 512

    repack_all<<<400, 256, 0, stream>>>(W1, W2, W3, ws);
    fused_mlp<<<512, 512, 0, stream>>>(content, motion, b1, b2, b3,
                                       w1p, w2p, w3p, out);
}

// Round 9
// 225.466 us; speedup vs baseline: 2.0705x; 1.0158x over previous
//
#include <hip/hip_runtime.h>

// I/O: float32 (per reference). Internal compute: bf16 MFMA (2%-relative
// threshold; measured absmax 0.0156 vs 0.0615 budget).
//
// R12 (resubmit; R8-round bench was an infra failure -- "container failed
// twice", no kernel evidence): strip to proven-good parts + T5 setprio.
// R11 post-mortem: the sched_barrier(0) fences forced rigid load/compute
// phase separation (sched_barrier(0) blocks ALL motion, including
// beneficial interleave); manual dbuf never survives compilation anyway
// (VGPR pinned at 64 across R10/R11). Every HIP-level schedule
// intervention lands 84-98us: the compiler's per-kt drain-then-compute
// rhythm is structural. What's NOT been tried: s_setprio around MFMA
// clusters (T5: +21-39% where wave role diversity exists; null only under
// barrier lockstep). Our L3 is 8 waves, ZERO barriers for ~73us straight
// -- the right regime. R12 = R0 structure + L1 content-dedup (attributed
// good in R11) + plain L3 loop (no dbuf, no fences) + setprio(1) around
// L2/L3 MFMA clusters, weights issued before LDS reads per step.
// Prediction: fused 89.1 -> 78-84us, dur -> 218-224. Falsifier: fused >=
// 86us => setprio null (m190-consistent), structure at ceiling; remaining
// levers: 32x32-MFMA restructure or stop.

typedef __attribute__((ext_vector_type(4))) float  floatx4;
typedef __attribute__((ext_vector_type(8))) short  shortx8;

__device__ __forceinline__ short f2bf(float f) {
    unsigned u = __builtin_bit_cast(unsigned, f);
    u += 0x7fffu + ((u >> 16) & 1u);   // RTNE
    return (short)(u >> 16);
}

__device__ __forceinline__ shortx8 cvt8(const float* __restrict__ p) {
    floatx4 a = *(const floatx4*)p;
    floatx4 b = *(const floatx4*)(p + 4);
    shortx8 r;
    r[0] = f2bf(a[0]); r[1] = f2bf(a[1]); r[2] = f2bf(a[2]); r[3] = f2bf(a[3]);
    r[4] = f2bf(b[0]); r[5] = f2bf(b[1]); r[6] = f2bf(b[2]); r[7] = f2bf(b[3]);
    return r;
}

// Single-launch repack of W1/W2/W3 (f32 row-major [K,N]) into bf16 MFMA-B
// fragment order. Tile rel=(nt*KT+kt): lane l holds
// B[kt*32+(l>>4)*8+j][nt*16+(l&15)], j=0..7, 16B contiguous per lane.
__global__ void repack_all(const float* __restrict__ W1,
                           const float* __restrict__ W2,
                           const float* __restrict__ W3,
                           short* __restrict__ ws) {
    int t = blockIdx.x * blockDim.x + threadIdx.x;
    int tile = t >> 6, lane = t & 63;
    const float* src; short* dst; int N, KT, rel;
    if (tile < 192)       { src = W1; dst = ws;                  N = 256;  KT = 12; rel = tile; }
    else if (tile < 448)  { src = W2; dst = ws + 98304;          N = 512;  KT = 8;  rel = tile - 192; }
    else if (tile < 1600) { src = W3; dst = ws + 98304 + 131072; N = 1152; KT = 16; rel = tile - 448; }
    else return;
    int nt = rel / KT, kt = rel - nt * KT;
    int col  = nt * 16 + (lane & 15);
    int row0 = kt * 32 + (lane >> 4) * 8;
    shortx8 v;
#pragma unroll
    for (int j = 0; j < 8; ++j) v[j] = f2bf(src[(row0 + j) * N + col]);
    *(shortx8*)(dst + rel * 512 + lane * 8) = v;
}

__global__ __launch_bounds__(512, 4) void fused_mlp(
    const float* __restrict__ content, const float* __restrict__ motion,
    const float* __restrict__ b1, const float* __restrict__ b2,
    const float* __restrict__ b3,
    const short* __restrict__ w1p, const short* __restrict__ w2p,
    const short* __restrict__ w3p, float* __restrict__ out)
{
    __shared__ short hbuf[64 * 520];   // h2 view: stride 520; h1 view: stride 264

    const int tid  = threadIdx.x;
    const int lane = tid & 63;
    const int w    = tid >> 6;        // wave 0..7: column-strip owner
    const int l15  = lane & 15;
    const int q    = lane >> 4;       // 0..3
    const int m0   = blockIdx.x * 64;
    const int bidx = m0 >> 9;

    // ---------------- Layer 1: X[64,384] @ W1 -> h1[64,256] ----------------
    {
        floatx4 accC[2] = {};          // content partial sum (token-independent)
        const float* crow = content + bidx * 256;
#pragma unroll
        for (int kt = 0; kt < 8; ++kt) {
            shortx8 a0 = cvt8(crow + kt * 32 + q * 8);   // identical across mt
#pragma unroll
            for (int nt = 0; nt < 2; ++nt) {
                shortx8 bf = *(const shortx8*)(w1p + ((w * 2 + nt) * 12 + kt) * 512 + lane * 8);
                accC[nt] = __builtin_amdgcn_mfma_f32_16x16x32_bf16(a0, bf, accC[nt], 0, 0, 0);
            }
        }
        floatx4 acc[4][2];
#pragma unroll
        for (int mt = 0; mt < 4; ++mt)
#pragma unroll
            for (int nt = 0; nt < 2; ++nt) acc[mt][nt] = accC[nt];
#pragma unroll
        for (int kt = 8; kt < 12; ++kt) {
            const int c0 = kt * 32 + q * 8;
            shortx8 a[4];
#pragma unroll
            for (int mt = 0; mt < 4; ++mt)
                a[mt] = cvt8(motion + (m0 + mt * 16 + l15) * 128 + (c0 - 256));
#pragma unroll
            for (int nt = 0; nt < 2; ++nt) {
                shortx8 bf = *(const shortx8*)(w1p + ((w * 2 + nt) * 12 + kt) * 512 + lane * 8);
#pragma unroll
                for (int mt = 0; mt < 4; ++mt)
                    acc[mt][nt] = __builtin_amdgcn_mfma_f32_16x16x32_bf16(a[mt], bf, acc[mt][nt], 0, 0, 0);
            }
        }
#pragma unroll
        for (int nt = 0; nt < 2; ++nt) {
            const int col = (w * 2 + nt) * 16 + l15;
            const float bias = b1[col];
#pragma unroll
            for (int mt = 0; mt < 4; ++mt)
#pragma unroll
            for (int r = 0; r < 4; ++r) {
                float v = acc[mt][nt][r] + bias;
                v = (v >= 0.f) ? v : 0.2f * v;
                hbuf[(mt * 16 + q * 4 + r) * 264 + col] = f2bf(v);
            }
        }
    }
    __syncthreads();

    // ---------------- Layer 2: h1[64,256] @ W2 -> h2[64,512] ----------------
    {
        floatx4 acc[4][4] = {};
#pragma unroll
        for (int kt = 0; kt < 8; ++kt) {
            // weights first (longest latency), then LDS fragments
            shortx8 bf[4];
#pragma unroll
            for (int nt = 0; nt < 4; ++nt)
                bf[nt] = *(const shortx8*)(w2p + ((w * 4 + nt) * 8 + kt) * 512 + lane * 8);
            shortx8 a[4];
#pragma unroll
            for (int mt = 0; mt < 4; ++mt)
                a[mt] = *(const shortx8*)(&hbuf[(mt * 16 + l15) * 264 + kt * 32 + q * 8]);
            __builtin_amdgcn_s_setprio(1);
#pragma unroll
            for (int nt = 0; nt < 4; ++nt)
#pragma unroll
                for (int mt = 0; mt < 4; ++mt)
                    acc[mt][nt] = __builtin_amdgcn_mfma_f32_16x16x32_bf16(a[mt], bf[nt], acc[mt][nt], 0, 0, 0);
            __builtin_amdgcn_s_setprio(0);
        }
        __syncthreads();   // all h1 reads complete before h2 overwrites buffer
#pragma unroll
        for (int nt = 0; nt < 4; ++nt) {
            const int col = (w * 4 + nt) * 16 + l15;
            const float bias = b2[col];
#pragma unroll
            for (int mt = 0; mt < 4; ++mt)
#pragma unroll
            for (int r = 0; r < 4; ++r) {
                float v = acc[mt][nt][r] + bias;
                v = (v >= 0.f) ? v : 0.2f * v;
                hbuf[(mt * 16 + q * 4 + r) * 520 + col] = f2bf(v);
            }
        }
    }
    __syncthreads();

    // -------- Layer 3: h2[64,512] @ W3 -> out[64,1152], 3 passes of 48 cols --------
    // Plain per-kt loop (no manual dbuf/fences); setprio(1) around the MFMA
    // cluster so MFMA-phase waves win SIMD arbitration over load-phase waves
    // (8 waves, no barriers in this entire stretch -> natural role diversity).
#pragma unroll 1
    for (int gi = 0; gi < 3; ++gi) {
        floatx4 acc[4][3] = {};   // 48 accs
        const short* w3b = w3p + (w * 9 + gi * 3) * 16 * 512 + lane * 8;  // + (nt*16+kt)*512
#pragma unroll 4
        for (int kt = 0; kt < 16; ++kt) {
            shortx8 bf[3];
#pragma unroll
            for (int nt = 0; nt < 3; ++nt)
                bf[nt] = *(const shortx8*)(w3b + (nt * 16 + kt) * 512);
            shortx8 a[4];
#pragma unroll
            for (int mt = 0; mt < 4; ++mt)
                a[mt] = *(const shortx8*)(&hbuf[(mt * 16 + l15) * 520 + kt * 32 + q * 8]);
            __builtin_amdgcn_s_setprio(1);
#pragma unroll
            for (int nt = 0; nt < 3; ++nt)
#pragma unroll
                for (int mt = 0; mt < 4; ++mt)
                    acc[mt][nt] = __builtin_amdgcn_mfma_f32_16x16x32_bf16(a[mt], bf[nt], acc[mt][nt], 0, 0, 0);
            __builtin_amdgcn_s_setprio(0);
        }
        // R0 epilogue: col = lane-consecutive -> 64B-coalesced scalar stores
#pragma unroll
        for (int nt = 0; nt < 3; ++nt) {
            const int col = (w * 9 + gi * 3 + nt) * 16 + l15;
            const float bias = b3[col];
#pragma unroll
            for (int mt = 0; mt < 4; ++mt)
#pragma unroll
            for (int r = 0; r < 4; ++r)
                out[(m0 + mt * 16 + q * 4 + r) * 1152 + col] = acc[mt][nt][r] + bias;
        }
    }
}

extern "C" void kernel_launch(void* const* d_in, const int* in_sizes, int n_in,
                              void* d_out, int out_size, void* d_ws, size_t ws_size,
                              hipStream_t stream) {
    const float* content = (const float*)d_in[0];  // [64,256]
    const float* motion  = (const float*)d_in[1];  // [64,512,128]
    const float* W1 = (const float*)d_in[2];       // [384,256]
    const float* b1 = (const float*)d_in[3];
    const float* W2 = (const float*)d_in[4];       // [256,512]
    const float* b2 = (const float*)d_in[5];
    const float* W3 = (const float*)d_in[6];       // [512,1152]
    const float* b3 = (const float*)d_in[7];
    float* out = (float*)d_out;

    short* ws  = (short*)d_ws;
    short* w1p = ws;                     // 192 tiles * 512 elems
    short* w2p = ws + 98304;             // 256 tiles * 512
    short* w3p = ws + 98304 + 131072;    // 1152 tiles * 512

    repack_all<<<400, 256, 0, stream>>>(W1, W2, W3, ws);
    fused_mlp<<<512, 512, 0, stream>>>(content, motion, b1, b2, b3,
                                       w1p, w2p, w3p, out);
}